// Round 14
// baseline (188.242 us; speedup 1.0000x reference)
//
#include <hip/hip_runtime.h>
#include <math.h>

typedef unsigned short u16;
typedef _Float16 f16;
typedef f16 f16x8 __attribute__((ext_vector_type(8)));
typedef __fp16 hp16x2 __attribute__((ext_vector_type(2)));
typedef float f32x4 __attribute__((ext_vector_type(4)));
typedef float f32x16 __attribute__((ext_vector_type(16)));
typedef unsigned u32x2 __attribute__((ext_vector_type(2)));

#define SEQ   2048
#define NH    16
#define HD    64
#define EMB   1024
#define NQKV  3072
#define BATCH 2
#define QSCALE 0.18033688f  // 0.125 * log2(e)

__device__ __forceinline__ u16 f2h(float f) {
  union { f16 h; u16 u; } w; w.h = (f16)f; return w.u;
}

// global -> LDS direct copy, 16 B per lane; dst = wave-uniform base + lane*16
__device__ __forceinline__ void gload16(const void* g, void* l) {
  __builtin_amdgcn_global_load_lds(
      (const __attribute__((address_space(1))) unsigned int*)g,
      (__attribute__((address_space(3))) unsigned int*)l, 16, 0, 0);
}

// ---------------------------------------------------------------------------
// Fused pre-pass kernel (R5): one launch does all three independent pre-passes
//   blocks [0, 2048):    X fp32 -> f16 flat copy
//   blocks [2048, 2816): Wqkv [K][N] -> Wt [N][K] f16, 64x64 tiles
//   blocks [2816, 3072): Wproj      -> Wpt,          64x64 tiles
// ---------------------------------------------------------------------------
__device__ __forceinline__ void cvt_wt_tile(const float* __restrict__ W,
                                            u16* __restrict__ Wt,
                                            int K, int N, int n0, int k0, int t) {
  __shared__ u16 T[64][68];
  const int rr = t >> 4, cc = (t & 15) << 2;
#pragma unroll
  for (int p = 0; p < 4; p++) {
    const int kr = p * 16 + rr;
    float4 v = *reinterpret_cast<const float4*>(&W[(size_t)(k0 + kr) * N + n0 + cc]);
    T[cc + 0][kr] = f2h(v.x); T[cc + 1][kr] = f2h(v.y);
    T[cc + 2][kr] = f2h(v.z); T[cc + 3][kr] = f2h(v.w);
  }
  __syncthreads();
#pragma unroll
  for (int p = 0; p < 4; p++) {
    const int nr = p * 16 + rr;
    union { u16 s[4]; unsigned long long d; } o;
    o.s[0] = T[nr][cc + 0]; o.s[1] = T[nr][cc + 1];
    o.s[2] = T[nr][cc + 2]; o.s[3] = T[nr][cc + 3];
    *reinterpret_cast<unsigned long long*>(&Wt[(size_t)(n0 + nr) * K + k0 + cc]) = o.d;
  }
}

__global__ __launch_bounds__(256) void k_pre(const float* __restrict__ X,
                                             u16* __restrict__ Xh,
                                             const float* __restrict__ Wqkv,
                                             u16* __restrict__ Wt,
                                             const float* __restrict__ Wproj,
                                             u16* __restrict__ Wpt) {
  const int b = blockIdx.x;
  const int t = threadIdx.x;
  if (b < 2048) {
    const size_t i = ((size_t)b * 256 + t) * 8;
    float4 a = *reinterpret_cast<const float4*>(&X[i]);
    float4 c = *reinterpret_cast<const float4*>(&X[i + 4]);
    union { hp16x2 h2[4]; float4 f; } pk;
    pk.h2[0] = __builtin_amdgcn_cvt_pkrtz(a.x, a.y);
    pk.h2[1] = __builtin_amdgcn_cvt_pkrtz(a.z, a.w);
    pk.h2[2] = __builtin_amdgcn_cvt_pkrtz(c.x, c.y);
    pk.h2[3] = __builtin_amdgcn_cvt_pkrtz(c.z, c.w);
    *reinterpret_cast<float4*>(&Xh[i]) = pk.f;
  } else if (b < 2048 + 768) {
    const int id = b - 2048;                 // old grid (48, 16)
    cvt_wt_tile(Wqkv, Wt, EMB, NQKV, (id % 48) << 6, (id / 48) << 6, t);
  } else {
    const int id = b - 2816;                 // old grid (16, 16)
    cvt_wt_tile(Wproj, Wpt, EMB, EMB, (id % 16) << 6, (id / 16) << 6, t);
  }
}

// ---------------------------------------------------------------------------
// Single-buffered m97-style core -- used by k_proj (R5/R8 proven config).
// ---------------------------------------------------------------------------
__device__ __forceinline__ void gemm_core_sb(const u16* __restrict__ Ag,
                                             const u16* __restrict__ Bg,
                                             int m0, int n0, int t,
                                             f32x4 acc[4][4]) {
  __shared__ __align__(16) u16 As[128 * 32];
  __shared__ __align__(16) u16 Bs[128 * 32];
  const int lane = t & 63, w = t >> 6;
  const int l15  = lane & 15, quad = lane >> 4;
  const int wm = w >> 1, wn = w & 1;
  const int srow  = lane >> 2;
  const int gslot = (lane & 3) ^ ((srow >> 1) & 3);
  const int xk    = (quad ^ ((l15 >> 1) & 3)) << 3;

  for (int k0 = 0; k0 < EMB; k0 += 32) {
    __syncthreads();
#pragma unroll
    for (int i = 0; i < 2; i++) {
      const int ca = w * 2 + i;
      const int arow = ca * 16 + srow;
      gload16(Ag + (size_t)(m0 + arow) * EMB + k0 + gslot * 8, &As[ca * 512]);
      gload16(Bg + (size_t)(n0 + arow) * EMB + k0 + gslot * 8, &Bs[ca * 512]);
    }
    __syncthreads();
    f16x8 af[4], bf[4];
#pragma unroll
    for (int s = 0; s < 4; s++)
      af[s] = *reinterpret_cast<const f16x8*>(&As[(wm * 64 + s * 16 + l15) * 32 + xk]);
#pragma unroll
    for (int s = 0; s < 4; s++)
      bf[s] = *reinterpret_cast<const f16x8*>(&Bs[(wn * 64 + s * 16 + l15) * 32 + xk]);
#pragma unroll
    for (int i = 0; i < 4; i++)
#pragma unroll
      for (int j = 0; j < 4; j++)
        acc[i][j] = __builtin_amdgcn_mfma_f32_16x16x32_f16(af[i], bf[j], acc[i][j], 0, 0, 0);
  }
}

// ---------------------------------------------------------------------------
// R11 k_qkv (kept): fragment-reuse geometry + in-LDS V^T transpose epilogue.
// ---------------------------------------------------------------------------
__global__ __launch_bounds__(128, 2) void k_qkv(const u16* __restrict__ Ag,
                                                const u16* __restrict__ Bg,
                                                const float* __restrict__ bias,
                                                u16* __restrict__ qo,
                                                u16* __restrict__ ko,
                                                u16* __restrict__ vo) {
  __shared__ __align__(16) u16 SM[4][128 * 32];   // As=SM[0..1], Bs=SM[2..3]
  const int t = threadIdx.x;
  const int lane = t & 63, w = t >> 6;            // w in {0,1}
  const int l15 = lane & 15, quad = lane >> 4;
  const int srow  = lane >> 2;
  const int gslot = (lane & 3) ^ ((srow >> 1) & 3);
  const int xk    = (quad ^ ((l15 >> 1) & 3)) << 3;
  const int id  = blockIdx.y * 24 + blockIdx.x;   // [0,768)
  const int xcd = id & 7, rr = id >> 3;           // rr in [0,96)
  const int n_t = 12 * (xcd & 1) + rr % 12;       // [0,24)
  const int m_t = 8 * (xcd >> 1) + rr / 12;       // [0,32)
  const int m0 = m_t << 7, n0 = n_t << 7;

  f32x4 acc[4][8];
#pragma unroll
  for (int i = 0; i < 4; i++)
#pragma unroll
    for (int j = 0; j < 8; j++) acc[i][j] = (f32x4){0.f, 0.f, 0.f, 0.f};

  auto STAGE = [&](int buf, int k0) {
#pragma unroll
    for (int i = 0; i < 4; i++) {
      const int ca = w * 4 + i;                   // chunk [0,8)
      const int arow = ca * 16 + srow;
      gload16(Ag + (size_t)(m0 + arow) * EMB + k0 + gslot * 8, &SM[buf][ca * 512]);
      gload16(Bg + (size_t)(n0 + arow) * EMB + k0 + gslot * 8, &SM[2 + buf][ca * 512]);
    }
  };

  STAGE(0, 0);
  __syncthreads();

  for (int kt = 0; kt < 32; ++kt) {               // EMB/32 K-steps
    if (kt + 1 < 32) STAGE((kt + 1) & 1, (kt + 1) * 32);
    const u16* Asb = SM[kt & 1];
    const u16* Bsb = SM[2 + (kt & 1)];
    f16x8 af[4], bf[8];
#pragma unroll
    for (int s = 0; s < 4; s++)
      af[s] = *reinterpret_cast<const f16x8*>(
          &Asb[(w * 64 + s * 16 + l15) * 32 + xk]);
#pragma unroll
    for (int s = 0; s < 8; s++)
      bf[s] = *reinterpret_cast<const f16x8*>(
          &Bsb[(s * 16 + l15) * 32 + xk]);
    __builtin_amdgcn_s_setprio(1);
#pragma unroll
    for (int i = 0; i < 4; i++)
#pragma unroll
      for (int j = 0; j < 8; j++)
        acc[i][j] = __builtin_amdgcn_mfma_f32_16x16x32_f16(af[i], bf[j],
                                                           acc[i][j], 0, 0, 0);
    __builtin_amdgcn_s_setprio(0);
    __syncthreads();                              // drains prefetch + read-done
  }
  // after final barrier: all LDS reads done, SM is dead -> reusable

  if (n0 >= 2048) {
    // ---- V block: transpose in LDS, write V^T coalesced ----
    u16* T = &SM[0][0];
#pragma unroll
    for (int j = 0; j < 8; j++) {
      const int c  = n0 + j * 16 + l15;
      const float bv = bias[c];
      const int dl = j * 16 + l15;                // c - n0
#pragma unroll
      for (int i = 0; i < 4; i++) {
#pragma unroll
        for (int r2 = 0; r2 < 4; r2++) {
          const int ml = w * 64 + i * 16 + quad * 4 + r2;
          T[dl * 128 + ((((ml >> 3) ^ (dl & 15)) << 3) | (ml & 7))] =
              f2h(acc[i][j][r2] + bv);
        }
      }
    }
    __syncthreads();
    const int bb = m0 >> 11, nb = m0 & (SEQ - 1);
    const int cg = lane & 15;                     // 16B-granule column
#pragma unroll
    for (int it = 0; it < 16; ++it) {
      const int row = w * 64 + it * 4 + (lane >> 4);   // dl in [0,128)
      union { f16x8 v; float4 f; } u;
      u.v = *reinterpret_cast<const f16x8*>(
          &T[row * 128 + ((cg ^ (row & 15)) << 3)]);
      const int c = n0 + row;
      const int h = (c >> 6) & 15, d = c & 63;
      *reinterpret_cast<float4*>(
          &vo[((size_t)(bb * NH + h) * HD + d) * SEQ + nb + cg * 8]) = u.f;
    }
  } else {
    // ---- q/k block: original epilogue (full-line coverage, coalesces OK) --
#pragma unroll
    for (int j = 0; j < 8; j++) {
      const int c = n0 + j * 16 + l15;
      const int which = c >> 10, h = (c >> 6) & 15, d = c & 63;
      const float bv = bias[c];
      const float sc = (which == 0) ? QSCALE : 1.0f;
#pragma unroll
      for (int i = 0; i < 4; i++) {
#pragma unroll
        for (int r2 = 0; r2 < 4; r2++) {
          const int m  = m0 + w * 64 + i * 16 + quad * 4 + r2;
          const int bb = m >> 11, n = m & (SEQ - 1);
          const u16 val = f2h((acc[i][j][r2] + bv) * sc);
          if (which == 1)
            ko[((((size_t)bb * NH + h) * SEQ) + n) * HD + d] = val;
          else
            qo[((((size_t)bb * NH + h) * SEQ) + n) * HD + d] = val;
        }
      }
    }
  }
}

// Proj: ao[4096,1024] f16 @ Wpt^T + bias -> out fp32  (exact R5/R8 form)
__global__ __launch_bounds__(256) void k_proj(const u16* __restrict__ Ag,
                                              const u16* __restrict__ Bg,
                                              const float* __restrict__ bias,
                                              float* __restrict__ out) {
  const int t = threadIdx.x;
  const int lane = t & 63, w = t >> 6;
  const int l15 = lane & 15, quad = lane >> 4;
  const int wm = w >> 1, wn = w & 1;
  const int m0 = blockIdx.y << 7, n0 = blockIdx.x << 7;
  f32x4 acc[4][4];
#pragma unroll
  for (int i = 0; i < 4; i++)
#pragma unroll
    for (int j = 0; j < 4; j++) acc[i][j] = (f32x4){0.f, 0.f, 0.f, 0.f};
  gemm_core_sb(Ag, Bg, m0, n0, t, acc);
#pragma unroll
  for (int j = 0; j < 4; j++) {
    const int c = n0 + wn * 64 + j * 16 + l15;
    const float bv = bias[c];
#pragma unroll
    for (int i = 0; i < 4; i++) {
#pragma unroll
      for (int r2 = 0; r2 < 4; r2++) {
        const int m = m0 + wm * 64 + i * 16 + quad * 4 + r2;
        out[(size_t)m * EMB + c] = acc[i][j][r2] + bv;
      }
    }
  }
}

// ---------------------------------------------------------------------------
// R14 k_attn = R11 structure + QK^T HOIST: both S^T sub-tiles' MFMAs issue
// before either softmax phase. Old order QK0->SM0->PV0->QK1->SM1->PV1 left
// SM0 (32 quarter-rate exp2 + packs) with no independent MFMA in flight;
// new order QK0,QK1 -> SM0 -> PV0 -> SM1 -> PV1 lets QK1 retire under SM0
// and SM1 issue under PV0 (MFMA/VALU pipes co-issue, m114). +16 VGPR
// (cq0+cq1 both live), no sync/layout change, bit-identical math.
// ---------------------------------------------------------------------------
__global__ __launch_bounds__(512, 4) void k_attn(const u16* __restrict__ Qg,
                                                 const u16* __restrict__ Kg,
                                                 const u16* __restrict__ Vtg,
                                                 u16* __restrict__ AO) {
  __shared__ __align__(16) u16 KV[2][2][2][64 * 64];
  __shared__ float Lx[256];                          // lsum exchange
  const int t    = threadIdx.x;
  const int lane = t & 63, w = t >> 6;
  const int grp  = w >> 2, wl = w & 3;               // kv-group, wave-in-group
  const int l31  = lane & 31, hi = lane >> 5;
  const int id   = blockIdx.y * 16 + blockIdx.x;     // 512 blocks, 512%8==0
  const int swz  = ((id & 7) << 6) | (id >> 3);
  const int bh   = swz >> 4;
  const int q0   = (swz & 15) << 7;
  const size_t base = (size_t)bh * SEQ * HD;         // == bh*HD*SEQ for Vt

  f16x8 qf[4];
  {
    const u16* qp = Qg + base + (size_t)(q0 + 32 * wl + l31) * HD + hi * 8;
#pragma unroll
    for (int c = 0; c < 4; c++) {
      union { float4 f; f16x8 v; } fu;
      fu.f = *reinterpret_cast<const float4*>(qp + c * 16);
      qf[c] = fu.v;
    }
  }

  f32x16 O0 = {}, O1 = {};
  float lsum = 0.f;
  const int fsw = (l31 >> 1) & 7;             // fragment-read swizzle
  const int srw = lane >> 3, ssl = lane & 7;  // staging row/slot
  const int kbeg = grp << 10;                 // group's kv-half start
  const int kend = kbeg + (SEQ / 2);

  auto STAGE = [&](int buf, int kt) {
    u16* Ksb = KV[buf][grp][0];
    u16* Vsb = KV[buf][grp][1];
#pragma unroll
    for (int i = 0; i < 2; i++) {
      const int ca  = wl * 2 + i;             // 8-row chunk 0..7
      const int row = ca * 8 + srw;
      const int sg  = (ssl ^ ((row >> 1) & 7)) << 3;
      gload16(Kg  + base + (size_t)(kt + row) * HD + sg, &Ksb[ca * 512]);
      gload16(Vtg + base + (size_t)row * SEQ + kt + sg,  &Vsb[ca * 512]);
    }
  };

  STAGE(0, kbeg);
  __syncthreads();

  int cur = 0;
  for (int kt = kbeg; kt < kend; kt += 64) {
    if (kt + 64 < kend) STAGE(cur ^ 1, kt + 64);
    const u16* Ks = KV[cur][grp][0];
    const u16* Vs = KV[cur][grp][1];

    // ---- QK^T for BOTH kv sub-tiles first (independent MFMA clusters) ----
    f32x16 cq0 = {}, cq1 = {};
    __builtin_amdgcn_s_setprio(1);
#pragma unroll
    for (int cc = 0; cc < 4; cc++) {
      f16x8 kf0 = *reinterpret_cast<const f16x8*>(
          &Ks[l31 * 64 + (((cc * 2 + hi) ^ fsw) << 3)]);
      f16x8 kf1 = *reinterpret_cast<const f16x8*>(
          &Ks[(32 + l31) * 64 + (((cc * 2 + hi) ^ fsw) << 3)]);
      cq0 = __builtin_amdgcn_mfma_f32_32x32x16_f16(kf0, qf[cc], cq0, 0, 0, 0);
      cq1 = __builtin_amdgcn_mfma_f32_32x32x16_f16(kf1, qf[cc], cq1, 0, 0, 0);
    }
    __builtin_amdgcn_s_setprio(0);

    // ---- SM+PV per sub-tile; SM1 can overlap PV0 (independent) ----
#pragma unroll
    for (int sk = 0; sk < 2; sk++) {
      const f32x16& c = sk ? cq1 : cq0;
      unsigned pw[4][2];
#pragma unroll
      for (int g = 0; g < 4; g++) {
        const float p0 = __builtin_amdgcn_exp2f(c[4 * g + 0]);
        const float p1 = __builtin_amdgcn_exp2f(c[4 * g + 1]);
        const float p2 = __builtin_amdgcn_exp2f(c[4 * g + 2]);
        const float p3 = __builtin_amdgcn_exp2f(c[4 * g + 3]);
        lsum += (p0 + p1) + (p2 + p3);
        union { hp16x2 h; unsigned u; } w0, w1;
        w0.h = __builtin_amdgcn_cvt_pkrtz(p0, p1);
        w1.h = __builtin_amdgcn_cvt_pkrtz(p2, p3);
        pw[g][0] = w0.u; pw[g][1] = w1.u;
      }
      __builtin_amdgcn_s_setprio(1);
#pragma unroll
      for (int s = 0; s < 2; s++) {
        u32x2 r02 = __builtin_amdgcn_permlane32_swap(
            pw[2 * s][0], pw[2 * s + 1][0], false, false);
        u32x2 r13 = __builtin_amdgcn_permlane32_swap(
            pw[2 * s][1], pw[2 * s + 1][1], false, false);
        union { unsigned u[4]; f16x8 v; } fr;
        fr.u[0] = r02.x;
        fr.u[1] = r13.x;
        fr.u[2] = r02.y;
        fr.u[3] = r13.y;
        const int cc = sk * 2 + s;
        f16x8 vf0 = *reinterpret_cast<const f16x8*>(
            &Vs[l31 * 64 + (((cc * 2 + hi) ^ fsw) << 3)]);
        f16x8 vf1 = *reinterpret_cast<const f16x8*>(
            &Vs[(32 + l31) * 64 + (((cc * 2 + hi) ^ fsw) << 3)]);
        O0 = __builtin_amdgcn_mfma_f32_32x32x16_f16(fr.v, vf0, O0, 0, 0, 0);
        O1 = __builtin_amdgcn_mfma_f32_32x32x16_f16(fr.v, vf1, O1, 0, 0, 0);
      }
      __builtin_amdgcn_s_setprio(0);
    }
    __syncthreads();
    cur ^= 1;
  }

  float* Xch = reinterpret_cast<float*>(&KV[0][0][0][0]);  // 8192 f32 = 32 KB
  const int li = wl * 64 + lane;
  if (grp == 1) {
#pragma unroll
    for (int g4 = 0; g4 < 4; g4++) {
      f32x4 v0 = { O0[4 * g4 + 0], O0[4 * g4 + 1], O0[4 * g4 + 2], O0[4 * g4 + 3] };
      *reinterpret_cast<f32x4*>(&Xch[(g4 * 256 + li) * 4]) = v0;
      f32x4 v1 = { O1[4 * g4 + 0], O1[4 * g4 + 1], O1[4 * g4 + 2], O1[4 * g4 + 3] };
      *reinterpret_cast<f32x4*>(&Xch[((4 + g4) * 256 + li) * 4]) = v1;
    }
    Lx[li] = lsum;
  }
  __syncthreads();
  if (grp == 0) {
#pragma unroll
    for (int g4 = 0; g4 < 4; g4++) {
      f32x4 v0 = *reinterpret_cast<const f32x4*>(&Xch[(g4 * 256 + li) * 4]);
      f32x4 v1 = *reinterpret_cast<const f32x4*>(&Xch[((4 + g4) * 256 + li) * 4]);
#pragma unroll
      for (int j = 0; j < 4; j++) {
        O0[4 * g4 + j] += v0[j];
        O1[4 * g4 + j] += v1[j];
      }
    }
    lsum += Lx[li];
    lsum += __shfl_xor(lsum, 32);
    const int b = bh >> 4, h = bh & 15;
#pragma unroll
    for (int g = 0; g < 4; g++) {
#pragma unroll
      for (int rr = 0; rr < 4; rr++) {
        const int r = g * 4 + rr;
        const int qrow = rr + 8 * g + 4 * hi;
        const float inv = 1.f / __shfl(lsum, qrow, 64);
        const int n = q0 + 32 * wl + qrow;
        u16* dst = AO + ((size_t)(b * SEQ + n)) * EMB + h * HD;
        dst[l31]      = f2h(O0[r] * inv);
        dst[32 + l31] = f2h(O1[r] * inv);
      }
    }
  }
}

extern "C" void kernel_launch(void* const* d_in, const int* in_sizes, int n_in,
                              void* d_out, int out_size, void* d_ws, size_t ws_size,
                              hipStream_t stream) {
  (void)in_sizes; (void)n_in; (void)out_size; (void)ws_size;
  const float* x     = (const float*)d_in[0];
  const float* Wqkv  = (const float*)d_in[1];
  const float* bqkv  = (const float*)d_in[2];
  const float* Wproj = (const float*)d_in[3];
  const float* bproj = (const float*)d_in[4];
  float* out = (float*)d_out;

  const size_t NE = (size_t)BATCH * SEQ * EMB;       // 4,194,304
  u16* q    = (u16*)d_ws;
  u16* k    = q + NE;
  u16* vt   = k + NE;                                // [B,H,D,N]
  u16* aoxh = vt + NE;                               // ao aliases Xh
  u16* Wt   = aoxh + NE;
  u16* Wpt  = Wt + (size_t)NQKV * EMB;

  // fused pre-pass: 2048 (cvt_x) + 768 (Wqkv) + 256 (Wproj) blocks
  k_pre<<<3072, 256, 0, stream>>>(x, aoxh, Wqkv, Wt, Wproj, Wpt);

  dim3 gq(NQKV / 128, (BATCH * SEQ) / 128);          // 24 x 32 = 768 blocks
  k_qkv<<<gq, 128, 0, stream>>>(aoxh, Wt, bqkv, q, k, vt);

  dim3 ga(SEQ / 128, BATCH * NH);                    // 16 x 32
  k_attn<<<ga, 512, 0, stream>>>(q, k, vt, aoxh);

  dim3 gp(EMB / 128, (BATCH * SEQ) / 128);           // 8 x 32
  k_proj<<<gp, 256, 0, stream>>>(aoxh, Wpt, bproj, out);
}

// Round 15
// 183.967 us; speedup vs baseline: 1.0232x; 1.0232x over previous
//
#include <hip/hip_runtime.h>
#include <math.h>

typedef unsigned short u16;
typedef _Float16 f16;
typedef f16 f16x8 __attribute__((ext_vector_type(8)));
typedef __fp16 hp16x2 __attribute__((ext_vector_type(2)));
typedef float f32x4 __attribute__((ext_vector_type(4)));
typedef float f32x16 __attribute__((ext_vector_type(16)));
typedef unsigned u32x2 __attribute__((ext_vector_type(2)));

#define SEQ   2048
#define NH    16
#define HD    64
#define EMB   1024
#define NQKV  3072
#define BATCH 2
#define QSCALE 0.18033688f  // 0.125 * log2(e)

__device__ __forceinline__ u16 f2h(float f) {
  union { f16 h; u16 u; } w; w.h = (f16)f; return w.u;
}

// global -> LDS direct copy, 16 B per lane; dst = wave-uniform base + lane*16
__device__ __forceinline__ void gload16(const void* g, void* l) {
  __builtin_amdgcn_global_load_lds(
      (const __attribute__((address_space(1))) unsigned int*)g,
      (__attribute__((address_space(3))) unsigned int*)l, 16, 0, 0);
}

// ---------------------------------------------------------------------------
// Fused pre-pass kernel (R5): one launch does all three independent pre-passes
//   blocks [0, 2048):    X fp32 -> f16 flat copy
//   blocks [2048, 2816): Wqkv [K][N] -> Wt [N][K] f16, 64x64 tiles
//   blocks [2816, 3072): Wproj      -> Wpt,          64x64 tiles
// ---------------------------------------------------------------------------
__device__ __forceinline__ void cvt_wt_tile(const float* __restrict__ W,
                                            u16* __restrict__ Wt,
                                            int K, int N, int n0, int k0, int t) {
  __shared__ u16 T[64][68];
  const int rr = t >> 4, cc = (t & 15) << 2;
#pragma unroll
  for (int p = 0; p < 4; p++) {
    const int kr = p * 16 + rr;
    float4 v = *reinterpret_cast<const float4*>(&W[(size_t)(k0 + kr) * N + n0 + cc]);
    T[cc + 0][kr] = f2h(v.x); T[cc + 1][kr] = f2h(v.y);
    T[cc + 2][kr] = f2h(v.z); T[cc + 3][kr] = f2h(v.w);
  }
  __syncthreads();
#pragma unroll
  for (int p = 0; p < 4; p++) {
    const int nr = p * 16 + rr;
    union { u16 s[4]; unsigned long long d; } o;
    o.s[0] = T[nr][cc + 0]; o.s[1] = T[nr][cc + 1];
    o.s[2] = T[nr][cc + 2]; o.s[3] = T[nr][cc + 3];
    *reinterpret_cast<unsigned long long*>(&Wt[(size_t)(n0 + nr) * K + k0 + cc]) = o.d;
  }
}

__global__ __launch_bounds__(256) void k_pre(const float* __restrict__ X,
                                             u16* __restrict__ Xh,
                                             const float* __restrict__ Wqkv,
                                             u16* __restrict__ Wt,
                                             const float* __restrict__ Wproj,
                                             u16* __restrict__ Wpt) {
  const int b = blockIdx.x;
  const int t = threadIdx.x;
  if (b < 2048) {
    const size_t i = ((size_t)b * 256 + t) * 8;
    float4 a = *reinterpret_cast<const float4*>(&X[i]);
    float4 c = *reinterpret_cast<const float4*>(&X[i + 4]);
    union { hp16x2 h2[4]; float4 f; } pk;
    pk.h2[0] = __builtin_amdgcn_cvt_pkrtz(a.x, a.y);
    pk.h2[1] = __builtin_amdgcn_cvt_pkrtz(a.z, a.w);
    pk.h2[2] = __builtin_amdgcn_cvt_pkrtz(c.x, c.y);
    pk.h2[3] = __builtin_amdgcn_cvt_pkrtz(c.z, c.w);
    *reinterpret_cast<float4*>(&Xh[i]) = pk.f;
  } else if (b < 2048 + 768) {
    const int id = b - 2048;                 // old grid (48, 16)
    cvt_wt_tile(Wqkv, Wt, EMB, NQKV, (id % 48) << 6, (id / 48) << 6, t);
  } else {
    const int id = b - 2816;                 // old grid (16, 16)
    cvt_wt_tile(Wproj, Wpt, EMB, EMB, (id % 16) << 6, (id / 16) << 6, t);
  }
}

// ---------------------------------------------------------------------------
// Single-buffered m97-style core -- used by k_proj (R5/R8 proven config).
// ---------------------------------------------------------------------------
__device__ __forceinline__ void gemm_core_sb(const u16* __restrict__ Ag,
                                             const u16* __restrict__ Bg,
                                             int m0, int n0, int t,
                                             f32x4 acc[4][4]) {
  __shared__ __align__(16) u16 As[128 * 32];
  __shared__ __align__(16) u16 Bs[128 * 32];
  const int lane = t & 63, w = t >> 6;
  const int l15  = lane & 15, quad = lane >> 4;
  const int wm = w >> 1, wn = w & 1;
  const int srow  = lane >> 2;
  const int gslot = (lane & 3) ^ ((srow >> 1) & 3);
  const int xk    = (quad ^ ((l15 >> 1) & 3)) << 3;

  for (int k0 = 0; k0 < EMB; k0 += 32) {
    __syncthreads();
#pragma unroll
    for (int i = 0; i < 2; i++) {
      const int ca = w * 2 + i;
      const int arow = ca * 16 + srow;
      gload16(Ag + (size_t)(m0 + arow) * EMB + k0 + gslot * 8, &As[ca * 512]);
      gload16(Bg + (size_t)(n0 + arow) * EMB + k0 + gslot * 8, &Bs[ca * 512]);
    }
    __syncthreads();
    f16x8 af[4], bf[4];
#pragma unroll
    for (int s = 0; s < 4; s++)
      af[s] = *reinterpret_cast<const f16x8*>(&As[(wm * 64 + s * 16 + l15) * 32 + xk]);
#pragma unroll
    for (int s = 0; s < 4; s++)
      bf[s] = *reinterpret_cast<const f16x8*>(&Bs[(wn * 64 + s * 16 + l15) * 32 + xk]);
#pragma unroll
    for (int i = 0; i < 4; i++)
#pragma unroll
      for (int j = 0; j < 4; j++)
        acc[i][j] = __builtin_amdgcn_mfma_f32_16x16x32_f16(af[i], bf[j], acc[i][j], 0, 0, 0);
  }
}

// ---------------------------------------------------------------------------
// R11 k_qkv (kept): fragment-reuse geometry (128 thr, 2 waves, acc[4][8],
// 0.375 ds_reads/MFMA, dbuf, prefetch-first, XCD super-tile swizzle) +
// in-LDS V^T transpose epilogue (fixes 2B-stride-4KB write amplification).
// ---------------------------------------------------------------------------
__global__ __launch_bounds__(128, 2) void k_qkv(const u16* __restrict__ Ag,
                                                const u16* __restrict__ Bg,
                                                const float* __restrict__ bias,
                                                u16* __restrict__ qo,
                                                u16* __restrict__ ko,
                                                u16* __restrict__ vo) {
  __shared__ __align__(16) u16 SM[4][128 * 32];   // As=SM[0..1], Bs=SM[2..3]
  const int t = threadIdx.x;
  const int lane = t & 63, w = t >> 6;            // w in {0,1}
  const int l15 = lane & 15, quad = lane >> 4;
  const int srow  = lane >> 2;
  const int gslot = (lane & 3) ^ ((srow >> 1) & 3);
  const int xk    = (quad ^ ((l15 >> 1) & 3)) << 3;
  const int id  = blockIdx.y * 24 + blockIdx.x;   // [0,768)
  const int xcd = id & 7, rr = id >> 3;           // rr in [0,96)
  const int n_t = 12 * (xcd & 1) + rr % 12;       // [0,24)
  const int m_t = 8 * (xcd >> 1) + rr / 12;       // [0,32)
  const int m0 = m_t << 7, n0 = n_t << 7;

  f32x4 acc[4][8];
#pragma unroll
  for (int i = 0; i < 4; i++)
#pragma unroll
    for (int j = 0; j < 8; j++) acc[i][j] = (f32x4){0.f, 0.f, 0.f, 0.f};

  auto STAGE = [&](int buf, int k0) {
#pragma unroll
    for (int i = 0; i < 4; i++) {
      const int ca = w * 4 + i;                   // chunk [0,8)
      const int arow = ca * 16 + srow;
      gload16(Ag + (size_t)(m0 + arow) * EMB + k0 + gslot * 8, &SM[buf][ca * 512]);
      gload16(Bg + (size_t)(n0 + arow) * EMB + k0 + gslot * 8, &SM[2 + buf][ca * 512]);
    }
  };

  STAGE(0, 0);
  __syncthreads();

  for (int kt = 0; kt < 32; ++kt) {               // EMB/32 K-steps
    if (kt + 1 < 32) STAGE((kt + 1) & 1, (kt + 1) * 32);
    const u16* Asb = SM[kt & 1];
    const u16* Bsb = SM[2 + (kt & 1)];
    f16x8 af[4], bf[8];
#pragma unroll
    for (int s = 0; s < 4; s++)
      af[s] = *reinterpret_cast<const f16x8*>(
          &Asb[(w * 64 + s * 16 + l15) * 32 + xk]);
#pragma unroll
    for (int s = 0; s < 8; s++)
      bf[s] = *reinterpret_cast<const f16x8*>(
          &Bsb[(s * 16 + l15) * 32 + xk]);
    __builtin_amdgcn_s_setprio(1);
#pragma unroll
    for (int i = 0; i < 4; i++)
#pragma unroll
      for (int j = 0; j < 8; j++)
        acc[i][j] = __builtin_amdgcn_mfma_f32_16x16x32_f16(af[i], bf[j],
                                                           acc[i][j], 0, 0, 0);
    __builtin_amdgcn_s_setprio(0);
    __syncthreads();                              // drains prefetch + read-done
  }
  // after final barrier: all LDS reads done, SM is dead -> reusable

  if (n0 >= 2048) {
    // ---- V block: transpose in LDS, write V^T coalesced ----
    u16* T = &SM[0][0];
#pragma unroll
    for (int j = 0; j < 8; j++) {
      const int c  = n0 + j * 16 + l15;
      const float bv = bias[c];
      const int dl = j * 16 + l15;                // c - n0
#pragma unroll
      for (int i = 0; i < 4; i++) {
#pragma unroll
        for (int r2 = 0; r2 < 4; r2++) {
          const int ml = w * 64 + i * 16 + quad * 4 + r2;
          T[dl * 128 + ((((ml >> 3) ^ (dl & 15)) << 3) | (ml & 7))] =
              f2h(acc[i][j][r2] + bv);
        }
      }
    }
    __syncthreads();
    const int bb = m0 >> 11, nb = m0 & (SEQ - 1);
    const int cg = lane & 15;                     // 16B-granule column
#pragma unroll
    for (int it = 0; it < 16; ++it) {
      const int row = w * 64 + it * 4 + (lane >> 4);   // dl in [0,128)
      union { f16x8 v; float4 f; } u;
      u.v = *reinterpret_cast<const f16x8*>(
          &T[row * 128 + ((cg ^ (row & 15)) << 3)]);
      const int c = n0 + row;
      const int h = (c >> 6) & 15, d = c & 63;
      *reinterpret_cast<float4*>(
          &vo[((size_t)(bb * NH + h) * HD + d) * SEQ + nb + cg * 8]) = u.f;
    }
  } else {
    // ---- q/k block: original epilogue (full-line coverage, coalesces OK) --
#pragma unroll
    for (int j = 0; j < 8; j++) {
      const int c = n0 + j * 16 + l15;
      const int which = c >> 10, h = (c >> 6) & 15, d = c & 63;
      const float bv = bias[c];
      const float sc = (which == 0) ? QSCALE : 1.0f;
#pragma unroll
      for (int i = 0; i < 4; i++) {
#pragma unroll
        for (int r2 = 0; r2 < 4; r2++) {
          const int m  = m0 + w * 64 + i * 16 + quad * 4 + r2;
          const int bb = m >> 11, n = m & (SEQ - 1);
          const u16 val = f2h((acc[i][j][r2] + bv) * sc);
          if (which == 1)
            ko[((((size_t)bb * NH + h) * SEQ) + n) * HD + d] = val;
          else
            qo[((((size_t)bb * NH + h) * SEQ) + n) * HD + d] = val;
        }
      }
    }
  }
}

// Proj: ao[4096,1024] f16 @ Wpt^T + bias -> out fp32  (exact R5/R8 form)
__global__ __launch_bounds__(256) void k_proj(const u16* __restrict__ Ag,
                                              const u16* __restrict__ Bg,
                                              const float* __restrict__ bias,
                                              float* __restrict__ out) {
  const int t = threadIdx.x;
  const int lane = t & 63, w = t >> 6;
  const int l15 = lane & 15, quad = lane >> 4;
  const int wm = w >> 1, wn = w & 1;
  const int m0 = blockIdx.y << 7, n0 = blockIdx.x << 7;
  f32x4 acc[4][4];
#pragma unroll
  for (int i = 0; i < 4; i++)
#pragma unroll
    for (int j = 0; j < 4; j++) acc[i][j] = (f32x4){0.f, 0.f, 0.f, 0.f};
  gemm_core_sb(Ag, Bg, m0, n0, t, acc);
#pragma unroll
  for (int j = 0; j < 4; j++) {
    const int c = n0 + wn * 64 + j * 16 + l15;
    const float bv = bias[c];
#pragma unroll
    for (int i = 0; i < 4; i++) {
#pragma unroll
      for (int r2 = 0; r2 < 4; r2++) {
        const int m = m0 + wm * 64 + i * 16 + quad * 4 + r2;
        out[(size_t)m * EMB + c] = acc[i][j][r2] + bv;
      }
    }
  }
}

// ---------------------------------------------------------------------------
// MFMA flash attention (R11-exact; twice independently measured at 187.2us
// total): 32x32x16 S^T formulation, 8 waves (2 kv-groups x 4), dbuf K/V,
// raw v_exp_f32, permlane32_swap P-exchange, XCD swizzle, setprio. R14's
// QK-hoist was clock-normalized neutral (compiler already interleaves);
// R12's 2-qset variant regressed (occupancy halved, serial SM chain doubled).
// ---------------------------------------------------------------------------
__global__ __launch_bounds__(512, 4) void k_attn(const u16* __restrict__ Qg,
                                                 const u16* __restrict__ Kg,
                                                 const u16* __restrict__ Vtg,
                                                 u16* __restrict__ AO) {
  __shared__ __align__(16) u16 KV[2][2][2][64 * 64];
  __shared__ float Lx[256];                          // lsum exchange
  const int t    = threadIdx.x;
  const int lane = t & 63, w = t >> 6;
  const int grp  = w >> 2, wl = w & 3;               // kv-group, wave-in-group
  const int l31  = lane & 31, hi = lane >> 5;
  const int id   = blockIdx.y * 16 + blockIdx.x;     // 512 blocks, 512%8==0
  const int swz  = ((id & 7) << 6) | (id >> 3);
  const int bh   = swz >> 4;
  const int q0   = (swz & 15) << 7;
  const size_t base = (size_t)bh * SEQ * HD;         // == bh*HD*SEQ for Vt

  f16x8 qf[4];
  {
    const u16* qp = Qg + base + (size_t)(q0 + 32 * wl + l31) * HD + hi * 8;
#pragma unroll
    for (int c = 0; c < 4; c++) {
      union { float4 f; f16x8 v; } fu;
      fu.f = *reinterpret_cast<const float4*>(qp + c * 16);
      qf[c] = fu.v;
    }
  }

  f32x16 O0 = {}, O1 = {};
  float lsum = 0.f;
  const int fsw = (l31 >> 1) & 7;             // fragment-read swizzle
  const int srw = lane >> 3, ssl = lane & 7;  // staging row/slot
  const int kbeg = grp << 10;                 // group's kv-half start
  const int kend = kbeg + (SEQ / 2);

  auto STAGE = [&](int buf, int kt) {
    u16* Ksb = KV[buf][grp][0];
    u16* Vsb = KV[buf][grp][1];
#pragma unroll
    for (int i = 0; i < 2; i++) {
      const int ca  = wl * 2 + i;             // 8-row chunk 0..7
      const int row = ca * 8 + srw;
      const int sg  = (ssl ^ ((row >> 1) & 7)) << 3;
      gload16(Kg  + base + (size_t)(kt + row) * HD + sg, &Ksb[ca * 512]);
      gload16(Vtg + base + (size_t)row * SEQ + kt + sg,  &Vsb[ca * 512]);
    }
  };

  STAGE(0, kbeg);
  __syncthreads();

  int cur = 0;
  for (int kt = kbeg; kt < kend; kt += 64) {
    if (kt + 64 < kend) STAGE(cur ^ 1, kt + 64);
    const u16* Ks = KV[cur][grp][0];
    const u16* Vs = KV[cur][grp][1];

#pragma unroll
    for (int sk = 0; sk < 2; sk++) {
      f32x16 c = {};
      __builtin_amdgcn_s_setprio(1);
#pragma unroll
      for (int cc = 0; cc < 4; cc++) {
        f16x8 kf = *reinterpret_cast<const f16x8*>(
            &Ks[(sk * 32 + l31) * 64 + (((cc * 2 + hi) ^ fsw) << 3)]);
        c = __builtin_amdgcn_mfma_f32_32x32x16_f16(kf, qf[cc], c, 0, 0, 0);
      }
      __builtin_amdgcn_s_setprio(0);
      unsigned pw[4][2];
#pragma unroll
      for (int g = 0; g < 4; g++) {
        const float p0 = __builtin_amdgcn_exp2f(c[4 * g + 0]);
        const float p1 = __builtin_amdgcn_exp2f(c[4 * g + 1]);
        const float p2 = __builtin_amdgcn_exp2f(c[4 * g + 2]);
        const float p3 = __builtin_amdgcn_exp2f(c[4 * g + 3]);
        lsum += (p0 + p1) + (p2 + p3);
        union { hp16x2 h; unsigned u; } w0, w1;
        w0.h = __builtin_amdgcn_cvt_pkrtz(p0, p1);
        w1.h = __builtin_amdgcn_cvt_pkrtz(p2, p3);
        pw[g][0] = w0.u; pw[g][1] = w1.u;
      }
      __builtin_amdgcn_s_setprio(1);
#pragma unroll
      for (int s = 0; s < 2; s++) {
        u32x2 r02 = __builtin_amdgcn_permlane32_swap(
            pw[2 * s][0], pw[2 * s + 1][0], false, false);
        u32x2 r13 = __builtin_amdgcn_permlane32_swap(
            pw[2 * s][1], pw[2 * s + 1][1], false, false);
        union { unsigned u[4]; f16x8 v; } fr;
        fr.u[0] = r02.x;
        fr.u[1] = r13.x;
        fr.u[2] = r02.y;
        fr.u[3] = r13.y;
        const int cc = sk * 2 + s;
        f16x8 vf0 = *reinterpret_cast<const f16x8*>(
            &Vs[l31 * 64 + (((cc * 2 + hi) ^ fsw) << 3)]);
        f16x8 vf1 = *reinterpret_cast<const f16x8*>(
            &Vs[(32 + l31) * 64 + (((cc * 2 + hi) ^ fsw) << 3)]);
        O0 = __builtin_amdgcn_mfma_f32_32x32x16_f16(fr.v, vf0, O0, 0, 0, 0);
        O1 = __builtin_amdgcn_mfma_f32_32x32x16_f16(fr.v, vf1, O1, 0, 0, 0);
      }
      __builtin_amdgcn_s_setprio(0);
    }
    __syncthreads();
    cur ^= 1;
  }

  float* Xch = reinterpret_cast<float*>(&KV[0][0][0][0]);  // 8192 f32 = 32 KB
  const int li = wl * 64 + lane;
  if (grp == 1) {
#pragma unroll
    for (int g4 = 0; g4 < 4; g4++) {
      f32x4 v0 = { O0[4 * g4 + 0], O0[4 * g4 + 1], O0[4 * g4 + 2], O0[4 * g4 + 3] };
      *reinterpret_cast<f32x4*>(&Xch[(g4 * 256 + li) * 4]) = v0;
      f32x4 v1 = { O1[4 * g4 + 0], O1[4 * g4 + 1], O1[4 * g4 + 2], O1[4 * g4 + 3] };
      *reinterpret_cast<f32x4*>(&Xch[((4 + g4) * 256 + li) * 4]) = v1;
    }
    Lx[li] = lsum;
  }
  __syncthreads();
  if (grp == 0) {
#pragma unroll
    for (int g4 = 0; g4 < 4; g4++) {
      f32x4 v0 = *reinterpret_cast<const f32x4*>(&Xch[(g4 * 256 + li) * 4]);
      f32x4 v1 = *reinterpret_cast<const f32x4*>(&Xch[((4 + g4) * 256 + li) * 4]);
#pragma unroll
      for (int j = 0; j < 4; j++) {
        O0[4 * g4 + j] += v0[j];
        O1[4 * g4 + j] += v1[j];
      }
    }
    lsum += Lx[li];
    lsum += __shfl_xor(lsum, 32);
    const int b = bh >> 4, h = bh & 15;
#pragma unroll
    for (int g = 0; g < 4; g++) {
#pragma unroll
      for (int rr = 0; rr < 4; rr++) {
        const int r = g * 4 + rr;
        const int qrow = rr + 8 * g + 4 * hi;
        const float inv = 1.f / __shfl(lsum, qrow, 64);
        const int n = q0 + 32 * wl + qrow;
        u16* dst = AO + ((size_t)(b * SEQ + n)) * EMB + h * HD;
        dst[l31]      = f2h(O0[r] * inv);
        dst[32 + l31] = f2h(O1[r] * inv);
      }
    }
  }
}

extern "C" void kernel_launch(void* const* d_in, const int* in_sizes, int n_in,
                              void* d_out, int out_size, void* d_ws, size_t ws_size,
                              hipStream_t stream) {
  (void)in_sizes; (void)n_in; (void)out_size; (void)ws_size;
  const float* x     = (const float*)d_in[0];
  const float* Wqkv  = (const float*)d_in[1];
  const float* bqkv  = (const float*)d_in[2];
  const float* Wproj = (const float*)d_in[3];
  const float* bproj = (const float*)d_in[4];
  float* out = (float*)d_out;

  const size_t NE = (size_t)BATCH * SEQ * EMB;       // 4,194,304
  u16* q    = (u16*)d_ws;
  u16* k    = q + NE;
  u16* vt   = k + NE;                                // [B,H,D,N]
  u16* aoxh = vt + NE;                               // ao aliases Xh
  u16* Wt   = aoxh + NE;
  u16* Wpt  = Wt + (size_t)NQKV * EMB;

  // fused pre-pass: 2048 (cvt_x) + 768 (Wqkv) + 256 (Wproj) blocks
  k_pre<<<3072, 256, 0, stream>>>(x, aoxh, Wqkv, Wt, Wproj, Wpt);

  dim3 gq(NQKV / 128, (BATCH * SEQ) / 128);          // 24 x 32 = 768 blocks
  k_qkv<<<gq, 128, 0, stream>>>(aoxh, Wt, bqkv, q, k, vt);

  dim3 ga(SEQ / 128, BATCH * NH);                    // 16 x 32
  k_attn<<<ga, 512, 0, stream>>>(q, k, vt, aoxh);

  dim3 gp(EMB / 128, (BATCH * SEQ) / 128);           // 8 x 32
  k_proj<<<gp, 256, 0, stream>>>(aoxh, Wpt, bproj, out);
}